// Round 9
// baseline (5257.452 us; speedup 1.0000x reference)
//
#include <hip/hip_runtime.h>
#include <hip/hip_bf16.h>

#define N_NODES 50000
#define N_EDGES 800000
#define IN_DIM 64
#define HID_DIM 128
#define OUT_DIM 64
#define NGRP 8
#define NSLC 4                                // feature slices (16 floats = 64B line)
#define NPB 16                                // nodes per agg chunk
#define ECAP 1024                             // staged edge cap per chunk
#define NE8 (NGRP * N_NODES)                  // 400000
#define NC8C ((NE8 + 255) / 256)              // 1563 scan chunks (group-major)
#define NCMC ((N_NODES + 255) / 256)          // 196 scan chunks (merged)
#define NBLK_L 1280                           // 5 blocks/CU; bounds guarantee 6 fit

// ---- device-global scratch ----
__device__ int g_in_f32;
__device__ int g_is64;
__device__ int g_src[N_EDGES];
__device__ int g_dst[N_EDGES];
__device__ int g_csr[N_EDGES];                // group-major partitioned CSR
__device__ int g_mcsr[N_EDGES];               // merged node-major CSR
__device__ int g_deg8[NE8];                   // [g][v]
__device__ int g_rowptr8[NE8 + 1];
__device__ int g_cursor8[NE8];
__device__ int g_mrp[N_NODES + 1];
__device__ int g_bsum[NC8C];
__device__ int g_bsum2[NCMC];
__device__ float g_dinv[N_NODES];
__device__ __align__(16) float g_W1f[IN_DIM * HID_DIM];
__device__ __align__(16) float g_W2f[HID_DIM * OUT_DIM];
__device__ __align__(16) float g_b1f[HID_DIM];
__device__ __align__(16) float g_b2f[OUT_DIM];
__device__ __align__(16) float g_hs1[(size_t)N_NODES * HID_DIM];   // aggz blocked [4][N][16]; later hs2 blocked
__device__ __align__(16) float g_agg1[(size_t)N_NODES * HID_DIM];  // zb blocked [4][N][16]; later h row-major

// ---- hierarchical grid-barrier state (zero-init; counts self-clean) ----
__device__ unsigned g_xcnt[8];
__device__ unsigned g_xgen[8];
__device__ unsigned g_gcnt;
__device__ unsigned g_ggen;

__device__ __forceinline__ float loadx(const void* p, int i, int f32) {
    if (f32) return ((const float*)p)[i];
    unsigned int u = ((unsigned int)((const unsigned short*)p)[i]) << 16;
    return __uint_as_float(u);
}

__device__ __forceinline__ unsigned ld_acq(unsigned* p) {
    return __hip_atomic_load(p, __ATOMIC_ACQUIRE, __HIP_MEMORY_SCOPE_AGENT);
}

// all blocks co-resident (launch_bounds + grid<=capacity) -> spin barrier is safe
__device__ __forceinline__ void gridbar(int bx, int nbx) {
    __threadfence();   // release this block's writes (device scope: wbl2)
    __syncthreads();
    if (threadIdx.x == 0) {
        int x = bx & 7;
        unsigned gen = ld_acq(&g_xgen[x]);
        unsigned a = __hip_atomic_fetch_add(&g_xcnt[x], 1u, __ATOMIC_ACQ_REL, __HIP_MEMORY_SCOPE_AGENT);
        if (a == (unsigned)(nbx - 1)) {              // xcd-group leader
            __hip_atomic_store(&g_xcnt[x], 0u, __ATOMIC_RELAXED, __HIP_MEMORY_SCOPE_AGENT);
            unsigned ggen = ld_acq(&g_ggen);
            unsigned ga = __hip_atomic_fetch_add(&g_gcnt, 1u, __ATOMIC_ACQ_REL, __HIP_MEMORY_SCOPE_AGENT);
            if (ga == 7u) {
                __hip_atomic_store(&g_gcnt, 0u, __ATOMIC_RELAXED, __HIP_MEMORY_SCOPE_AGENT);
                __hip_atomic_fetch_add(&g_ggen, 1u, __ATOMIC_ACQ_REL, __HIP_MEMORY_SCOPE_AGENT);
            } else {
                while (ld_acq(&g_ggen) == ggen) __builtin_amdgcn_s_sleep(2);
            }
            __hip_atomic_fetch_add(&g_xgen[x], 1u, __ATOMIC_ACQ_REL, __HIP_MEMORY_SCOPE_AGENT);
        } else {
            while (ld_acq(&g_xgen[x]) == gen) __builtin_amdgcn_s_sleep(2);
        }
    }
    __syncthreads();
    __threadfence();   // acquire side (inv stale L1/L2)
}

extern "C" __global__ void __launch_bounds__(256, 6)
gcn_uber(const void* __restrict__ z, const void* __restrict__ ei,
         const void* __restrict__ W1, const void* __restrict__ b1,
         const void* __restrict__ W2, const void* __restrict__ b2,
         void* __restrict__ out, int N, int E) {
    __shared__ __align__(16) float smf[2112];  // 8448 B, reused by every phase
    const int bx = blockIdx.x;
    const int t = threadIdx.x;
    const int gsz = gridDim.x * 256;
    const int gid = bx * 256 + t;
    const int nbx = gridDim.x >> 3;            // blocks per xcd group (grid%8==0)
    const int NE = NGRP * N;
    const int NC8 = (NE + 255) >> 8;
    const int NCM = (N + 255) >> 8;

    // ================= P0: detect (block 0) + zero deg8 =================
    if (bx == 0) {
        int* flags = (int*)smf;
        if (t < 2) flags[t] = 0;
        __syncthreads();
        const unsigned short* zw = (const unsigned short*)z;
        const unsigned int* ew = (const unsigned int*)ei;
        int hit = 0;
        for (int k = 0; k < 64; k++) {
            int i = 2 * ((t * 64 + k) * 97);
            if (((zw[i] >> 7) & 0xFF) == 0xFF) hit = 1;
        }
        if (hit) atomicOr(&flags[0], 1);
        int nz = 0;
        int step = E / 4096;
        for (int k = 0; k < 4; k++) {
            int idx = 1 + 2 * ((t * 4 + k) * step);
            if (ew[idx] != 0) nz = 1;
        }
        if (nz) atomicOr(&flags[1], 1);
        __syncthreads();
        if (t == 0) { g_in_f32 = flags[0]; g_is64 = (flags[1] == 0) ? 1 : 0; }
    }
    for (int i = gid; i < NE; i += gsz) g_deg8[i] = 0;
    gridbar(bx, nbx);

    // ================= P1: weight prep + edge convert/degree =================
    {
        int f32 = g_in_f32;
        for (int i = gid; i < IN_DIM * HID_DIM; i += gsz) g_W1f[i] = loadx(W1, i, f32);
        for (int i = gid; i < HID_DIM * OUT_DIM; i += gsz) g_W2f[i] = loadx(W2, i, f32);
        if (gid < HID_DIM) g_b1f[gid] = loadx(b1, gid, f32);
        if (gid < OUT_DIM) g_b2f[gid] = loadx(b2, gid, f32);
        int is64 = g_is64;
        int g = bx & (NGRP - 1);                 // fixed per physical block -> XCD-local
        for (int e = gid; e < E; e += gsz) {
            int s, d;
            if (is64) { const long long* p = (const long long*)ei; s = (int)p[e]; d = (int)p[E + e]; }
            else      { const int* p = (const int*)ei; s = p[e]; d = p[E + e]; }
            g_src[e] = s;
            g_dst[e] = d;
            atomicAdd(&g_deg8[g * N + d], 1);
        }
    }
    gridbar(bx, nbx);

    // ================= P2: chunk-local scans (deg8 + merged) =================
    {
        int* sc = (int*)smf;
        for (int vb = bx; vb < NC8; vb += gridDim.x) {
            int idx = (vb << 8) + t;
            int d = (idx < NE) ? g_deg8[idx] : 0;
            sc[t] = d;
            __syncthreads();
            for (int off = 1; off < 256; off <<= 1) {
                int v = (t >= off) ? sc[t - off] : 0;
                __syncthreads();
                sc[t] += v;
                __syncthreads();
            }
            if (idx < NE) g_rowptr8[idx] = sc[t] - d;  // local exclusive prefix
            if (t == 255) g_bsum[vb] = sc[255];
            __syncthreads();
        }
        for (int vb = bx; vb < NCM; vb += gridDim.x) {
            int idx = (vb << 8) + t;
            int d = 0;
            if (idx < N) {
#pragma unroll
                for (int g = 0; g < NGRP; g++) d += g_deg8[g * N + idx];
                g_dinv[idx] = rsqrtf((float)d + 1.0f);  // +1 = self loop
            }
            sc[t] = d;
            __syncthreads();
            for (int off = 1; off < 256; off <<= 1) {
                int v = (t >= off) ? sc[t - off] : 0;
                __syncthreads();
                sc[t] += v;
                __syncthreads();
            }
            if (idx < N) g_mrp[idx] = sc[t] - d;
            if (t == 255) g_bsum2[vb] = sc[255];
            __syncthreads();
        }
    }
    gridbar(bx, nbx);

    // ================= P3: fused prefix + addoff (both scans) =================
    {
        int* sc = (int*)smf;
        for (int vb = bx; vb < NC8; vb += gridDim.x) {
            int ps = 0;
            for (int i = t; i < vb; i += 256) ps += g_bsum[i];  // bsum tiny, L2-hot
            sc[t] = ps;
            __syncthreads();
            for (int off = 128; off > 0; off >>= 1) {
                if (t < off) sc[t] += sc[t + off];
                __syncthreads();
            }
            int prefix = sc[0];
            __syncthreads();
            int idx = (vb << 8) + t;
            if (idx < NE) {
                int base = g_rowptr8[idx] + prefix;
                g_rowptr8[idx] = base;
                g_cursor8[idx] = base;
            }
        }
        for (int vb = bx; vb < NCM; vb += gridDim.x) {
            int ps = 0;
            for (int i = t; i < vb; i += 256) ps += g_bsum2[i];
            sc[t] = ps;
            __syncthreads();
            for (int off = 128; off > 0; off >>= 1) {
                if (t < off) sc[t] += sc[t + off];
                __syncthreads();
            }
            int prefix = sc[0];
            __syncthreads();
            int idx = (vb << 8) + t;
            if (idx < N) g_mrp[idx] += prefix;
        }
        if (gid == 0) { g_rowptr8[NE] = E; g_mrp[N] = E; }
    }
    gridbar(bx, nbx);

    // ================= P4: scatter (XCD-partitioned writes) =================
    {
        int g = bx & (NGRP - 1);
        for (int e = gid; e < E; e += gsz) {
            int pos = atomicAdd(&g_cursor8[g * N + g_dst[e]], 1);
            g_csr[pos] = g_src[e];
        }
    }
    gridbar(bx, nbx);

    // ================= P5: merge CSR (wave/node) + zprep =================
    {
        int lane = t & 63;
        int wstride = gridDim.x << 2;
        for (int wid = (gid >> 6); wid < N; wid += wstride) {
            int mybeg = 0, mycnt = 0;
            if (lane < NGRP) {
                mybeg = g_rowptr8[lane * N + wid];
                mycnt = g_rowptr8[lane * N + wid + 1] - mybeg;
            }
            int incl = mycnt;
#pragma unroll
            for (int off = 1; off < NGRP; off <<= 1) {
                int v = __shfl_up(incl, off, 64);
                if (lane >= off) incl += v;
            }
            int myoff = incl - mycnt;
            int go[NGRP], gb[NGRP];
#pragma unroll
            for (int k = 0; k < NGRP; k++) {
                go[k] = __shfl(myoff, k, 64);
                gb[k] = __shfl(mybeg, k, 64);
            }
            int total = __shfl(incl, NGRP - 1, 64);
            int base = g_mrp[wid];
            for (int i = lane; i < total; i += 64) {
                int g = 0;
#pragma unroll
                for (int k = 1; k < NGRP; k++) g += (i >= go[k]);
                g_mcsr[base + i] = g_csr[gb[g] + i - go[g]];
            }
        }
        int f32 = g_in_f32;
        for (int i = gid; i < N * IN_DIM; i += gsz) {
            int node = i >> 6, c = i & 63;
            int s = c >> 4, off = c & 15;
            g_agg1[(size_t)s * (N * 16) + node * 16 + off] = loadx(z, i, f32) * g_dinv[node];
        }
    }
    gridbar(bx, nbx);

    // ================= P6: layer-1 sliced aggregation =================
    {
        int slc = bx & (NSLC - 1);               // bx%8=XCD => each XCD sees 1 slice
        const float* tab = g_agg1 + (size_t)slc * ((size_t)N * 16);
        float* dst = g_hs1 + (size_t)slc * ((size_t)N * 16);
        int* rp = (int*)smf;
        int* eidx = rp + 32;
        int lane = t & 63;
        int w4 = (t >> 6) * 4;
        int col = lane & 15, eslot = lane >> 4;
        int cstride = (gridDim.x >> 2) * NPB;
        for (int n0 = (bx >> 2) * NPB; n0 < N; n0 += cstride) {
            if (t <= NPB) { int idx = n0 + t; rp[t] = g_mrp[idx <= N ? idx : N]; }
            __syncthreads();
            int base = rp[0];
            int range = rp[NPB] - base;
            bool staged = (range <= ECAP);
            if (staged) for (int i = t; i < range; i += 256) eidx[i] = g_mcsr[base + i];
            __syncthreads();
            float res[4];
#pragma unroll
            for (int k = 0; k < 4; k++) {
                int jb = rp[w4 + k] - base + eslot;
                int je = rp[w4 + k + 1] - base;
                float a0 = 0.f, a1 = 0.f, a2 = 0.f, a3 = 0.f;
                int j = jb;
                if (staged) {
                    for (; j + 12 < je; j += 16) {
                        int i0 = eidx[j], i1 = eidx[j + 4], i2 = eidx[j + 8], i3 = eidx[j + 12];
                        a0 += tab[i0 * 16 + col];
                        a1 += tab[i1 * 16 + col];
                        a2 += tab[i2 * 16 + col];
                        a3 += tab[i3 * 16 + col];
                    }
                    for (; j < je; j += 4) a0 += tab[eidx[j] * 16 + col];
                } else {
                    for (; j < je; j += 4) a0 += tab[g_mcsr[base + j] * 16 + col];
                }
                float a = (a0 + a1) + (a2 + a3);
                a += __shfl_xor(a, 16, 64);
                a += __shfl_xor(a, 32, 64);
                res[k] = a;
            }
            if (lane < 16) {
#pragma unroll
                for (int k = 0; k < 4; k++) {
                    int nk = n0 + w4 + k;
                    if (nk < N)
                        dst[(size_t)nk * 16 + col] = (res[k] + tab[(size_t)nk * 16 + col]) * g_dinv[nk];
                }
            }
            __syncthreads();
        }
    }
    gridbar(bx, nbx);

    // ================= P7: gemm1  h = relu(aggz @ W1 + b1) =================
    {
        float* Zs = smf;  // [64k][33] transposed, 2112 floats
        int NV = (N + 31) >> 5;
        int cg = t & 31, rg = t >> 5;
        int c0 = cg * 4, r0 = rg * 4;
        for (int vb = bx; vb < NV; vb += gridDim.x) {
            int row0 = vb << 5;
#pragma unroll
            for (int s = 0; s < 2; s++) {
                int i = t + s * 256;
                int r = i >> 4, k4 = i & 15;
                int row = row0 + r;
                int g = k4 >> 2, off = (k4 & 3) * 4;  // blocked [4][N][16]
                float4 v = make_float4(0.f, 0.f, 0.f, 0.f);
                if (row < N) v = *(const float4*)&g_hs1[(size_t)g * (N * 16) + row * 16 + off];
                Zs[(g * 16 + off + 0) * 33 + r] = v.x;
                Zs[(g * 16 + off + 1) * 33 + r] = v.y;
                Zs[(g * 16 + off + 2) * 33 + r] = v.z;
                Zs[(g * 16 + off + 3) * 33 + r] = v.w;
            }
            __syncthreads();
            float acc[4][4] = {};
#pragma unroll 8
            for (int k = 0; k < IN_DIM; k++) {
                float b[4];
                *(float4*)b = *(const float4*)&g_W1f[k * HID_DIM + c0];
                float a[4];
                a[0] = Zs[k * 33 + r0];
                a[1] = Zs[k * 33 + r0 + 1];
                a[2] = Zs[k * 33 + r0 + 2];
                a[3] = Zs[k * 33 + r0 + 3];
#pragma unroll
                for (int i = 0; i < 4; i++)
#pragma unroll
                    for (int j = 0; j < 4; j++) acc[i][j] = fmaf(a[i], b[j], acc[i][j]);
            }
            float4 bias = *(const float4*)&g_b1f[c0];
#pragma unroll
            for (int i = 0; i < 4; i++) {
                int row = row0 + r0 + i;
                if (row < N) {
                    float4 v;
                    v.x = fmaxf(acc[i][0] + bias.x, 0.f);
                    v.y = fmaxf(acc[i][1] + bias.y, 0.f);
                    v.z = fmaxf(acc[i][2] + bias.z, 0.f);
                    v.w = fmaxf(acc[i][3] + bias.w, 0.f);
                    *(float4*)&g_agg1[(size_t)row * HID_DIM + c0] = v;
                }
            }
            __syncthreads();
        }
    }
    gridbar(bx, nbx);

    // ================= P8: gemm2  hs2 = (h @ W2) * dinv (blocked out) =================
    {
        float* Zs = smf;
        int NV = (N + 31) >> 5;
        int cg = t & 15, rg = t >> 4;
        int c0 = cg * 4, r0 = rg * 2;
        for (int vb = bx; vb < NV; vb += gridDim.x) {
            int row0 = vb << 5;
            float acc[2][4] = {};
            for (int kh = 0; kh < 2; kh++) {
                __syncthreads();
#pragma unroll
                for (int s = 0; s < 2; s++) {
                    int i = t + s * 256;
                    int r = i >> 4, k4 = i & 15;
                    int row = row0 + r;
                    float4 v = make_float4(0.f, 0.f, 0.f, 0.f);
                    if (row < N) v = *(const float4*)&g_agg1[(size_t)row * HID_DIM + kh * 64 + k4 * 4];
                    Zs[(k4 * 4 + 0) * 33 + r] = v.x;
                    Zs[(k4 * 4 + 1) * 33 + r] = v.y;
                    Zs[(k4 * 4 + 2) * 33 + r] = v.z;
                    Zs[(k4 * 4 + 3) * 33 + r] = v.w;
                }
                __syncthreads();
#pragma unroll 8
                for (int k2 = 0; k2 < 64; k2++) {
                    float b[4];
                    *(float4*)b = *(const float4*)&g_W2f[(kh * 64 + k2) * OUT_DIM + c0];
                    float a[2];
                    a[0] = Zs[k2 * 33 + r0];
                    a[1] = Zs[k2 * 33 + r0 + 1];
#pragma unroll
                    for (int i = 0; i < 2; i++)
#pragma unroll
                        for (int j = 0; j < 4; j++) acc[i][j] = fmaf(a[i], b[j], acc[i][j]);
                }
            }
            int g = cg >> 2, off = (cg & 3) * 4;  // blocked [4][N][16]
#pragma unroll
            for (int i = 0; i < 2; i++) {
                int row = row0 + r0 + i;
                if (row < N) {
                    float dn = g_dinv[row];
                    float4 v;
                    v.x = acc[i][0] * dn;
                    v.y = acc[i][1] * dn;
                    v.z = acc[i][2] * dn;
                    v.w = acc[i][3] * dn;
                    *(float4*)&g_hs1[(size_t)g * (N * 16) + row * 16 + off] = v;
                }
            }
            __syncthreads();
        }
    }
    gridbar(bx, nbx);

    // ================= P9: layer-2 sliced aggregation + bias + store =================
    {
        int slc = bx & (NSLC - 1);
        const float* tab = g_hs1 + (size_t)slc * ((size_t)N * 16);
        int* rp = (int*)smf;
        int* eidx = rp + 32;
        int lane = t & 63;
        int w4 = (t >> 6) * 4;
        int col = lane & 15, eslot = lane >> 4;
        int f32 = g_in_f32;
        float bias = g_b2f[slc * 16 + col];
        int cstride = (gridDim.x >> 2) * NPB;
        for (int n0 = (bx >> 2) * NPB; n0 < N; n0 += cstride) {
            if (t <= NPB) { int idx = n0 + t; rp[t] = g_mrp[idx <= N ? idx : N]; }
            __syncthreads();
            int base = rp[0];
            int range = rp[NPB] - base;
            bool staged = (range <= ECAP);
            if (staged) for (int i = t; i < range; i += 256) eidx[i] = g_mcsr[base + i];
            __syncthreads();
            float res[4];
#pragma unroll
            for (int k = 0; k < 4; k++) {
                int jb = rp[w4 + k] - base + eslot;
                int je = rp[w4 + k + 1] - base;
                float a0 = 0.f, a1 = 0.f, a2 = 0.f, a3 = 0.f;
                int j = jb;
                if (staged) {
                    for (; j + 12 < je; j += 16) {
                        int i0 = eidx[j], i1 = eidx[j + 4], i2 = eidx[j + 8], i3 = eidx[j + 12];
                        a0 += tab[i0 * 16 + col];
                        a1 += tab[i1 * 16 + col];
                        a2 += tab[i2 * 16 + col];
                        a3 += tab[i3 * 16 + col];
                    }
                    for (; j < je; j += 4) a0 += tab[eidx[j] * 16 + col];
                } else {
                    for (; j < je; j += 4) a0 += tab[g_mcsr[base + j] * 16 + col];
                }
                float a = (a0 + a1) + (a2 + a3);
                a += __shfl_xor(a, 16, 64);
                a += __shfl_xor(a, 32, 64);
                res[k] = a;
            }
            if (lane < 16) {
#pragma unroll
                for (int k = 0; k < 4; k++) {
                    int nk = n0 + w4 + k;
                    if (nk < N) {
                        float v = (res[k] + tab[(size_t)nk * 16 + col]) * g_dinv[nk] + bias;
                        int oc = nk * 64 + slc * 16 + col;
                        if (f32) ((float*)out)[oc] = v;
                        else ((__hip_bfloat16*)out)[oc] = __float2bfloat16(v);
                    }
                }
            }
            __syncthreads();
        }
    }
}

extern "C" void kernel_launch(void* const* d_in, const int* in_sizes, int n_in,
                              void* d_out, int out_size, void* d_ws, size_t ws_size,
                              hipStream_t stream) {
    const void* z  = d_in[0];
    const void* ei = d_in[1];
    const void* W1 = d_in[2];
    const void* b1 = d_in[3];
    const void* W2 = d_in[4];
    const void* b2 = d_in[5];

    const int N = in_sizes[0] / IN_DIM;  // 50000
    const int E = in_sizes[1] / 2;       // 800000

    gcn_uber<<<NBLK_L, 256, 0, stream>>>(z, ei, W1, b1, W2, b2, d_out, N, E);
}

// Round 10
// 320.541 us; speedup vs baseline: 16.4018x; 16.4018x over previous
//
#include <hip/hip_runtime.h>
#include <hip/hip_bf16.h>

#define N_NODES 50000
#define N_EDGES 800000
#define IN_DIM 64
#define HID_DIM 128
#define OUT_DIM 64
#define NGRP 8
#define NSLC 4                                // feature slices (16 floats = 64B line)
#define NPB 16                                // nodes per agg block
#define ECAP 1024                             // staged edge cap per block
#define NE8 (NGRP * N_NODES)                  // 400000
#define NC8C ((NE8 + 255) / 256)              // 1563 scan chunks (group-major)
#define NCMC ((N_NODES + 255) / 256)          // 196 scan chunks (merged)

// ---- device-global scratch ----
__device__ int g_in_f32;
__device__ int g_is64;
__device__ int g_csr[N_EDGES];                // group-major partitioned CSR
__device__ int g_mcsr[N_EDGES];               // merged node-major CSR
__device__ int g_deg8[NE8];                   // [g][v]
__device__ int g_rowptr8[NE8 + 1];
__device__ int g_cursor8[NE8];
__device__ int g_mrp[N_NODES + 1];
__device__ int g_bsum[NC8C];
__device__ int g_boff[NC8C];
__device__ int g_bsum2[NCMC];
__device__ int g_boff2[NCMC];
__device__ float g_dinv[N_NODES];
__device__ __align__(16) float g_W1f[IN_DIM * HID_DIM];
__device__ __align__(16) float g_W2f[HID_DIM * OUT_DIM];
__device__ __align__(16) float g_b1f[HID_DIM];
__device__ __align__(16) float g_b2f[OUT_DIM];
// g_hs1: aggz out blocked [4][N][16]; then hs2 blocked [4][N][16] (in-place per-row swap in gemm_fused)
__device__ __align__(16) float g_hs1[(size_t)N_NODES * IN_DIM];
// g_agg1: zb blocked [4][N][16] (dinv-scaled z)
__device__ __align__(16) float g_agg1[(size_t)N_NODES * IN_DIM];

__device__ __forceinline__ float loadx(const void* p, int i, int f32) {
    if (f32) return ((const float*)p)[i];
    unsigned int u = ((unsigned int)((const unsigned short*)p)[i]) << 16;
    return __uint_as_float(u);
}

// ---- K1: zero deg8 (grid) + dtype/index detect (block 0) ----
__global__ __launch_bounds__(256) void zerodet_kernel(const unsigned short* __restrict__ zw,
                                                      const unsigned int* __restrict__ ew,
                                                      int NE, int E) {
    int idx = blockIdx.x * 256 + threadIdx.x;
    if (idx < NE) g_deg8[idx] = 0;
    if (blockIdx.x == 0) {
        __shared__ int flags[2];
        int t = threadIdx.x;
        if (t < 2) flags[t] = 0;
        __syncthreads();
        int hit = 0;
        for (int k = 0; k < 64; k++) {
            int i = 2 * ((t * 64 + k) * 97);
            if (((zw[i] >> 7) & 0xFF) == 0xFF) hit = 1;
        }
        if (hit) atomicOr(&flags[0], 1);
        int nz = 0;
        int step = E / 4096;
        for (int k = 0; k < 4; k++) {
            int i = 1 + 2 * ((t * 4 + k) * step);
            if (ew[i] != 0) nz = 1;
        }
        if (nz) atomicOr(&flags[1], 1);
        __syncthreads();
        if (t == 0) { g_in_f32 = flags[0]; g_is64 = (flags[1] == 0) ? 1 : 0; }
    }
}

// ---- K2: per-group degree count (dst read direct from ei) + weight/bias f32 prep ----
__global__ __launch_bounds__(256) void degprep_kernel(const void* __restrict__ ei,
                                                      const void* __restrict__ W1, const void* __restrict__ b1,
                                                      const void* __restrict__ W2, const void* __restrict__ b2,
                                                      int N, int E) {
    int e = blockIdx.x * 256 + threadIdx.x;
    int f32 = g_in_f32;
    if (e < IN_DIM * HID_DIM) g_W1f[e] = loadx(W1, e, f32);
    if (e < HID_DIM * OUT_DIM) g_W2f[e] = loadx(W2, e, f32);
    if (e < HID_DIM) g_b1f[e] = loadx(b1, e, f32);
    if (e < OUT_DIM) g_b2f[e] = loadx(b2, e, f32);
    if (e < E) {
        int d = g_is64 ? (int)((const long long*)ei)[E + e] : ((const int*)ei)[E + e];
        int g = blockIdx.x & (NGRP - 1);          // round-robin -> XCD-local counters
        atomicAdd(&g_deg8[g * N + d], 1);
    }
}

// ---- K3: chunk-local scans: deg8 -> rowptr8-local + bsum; merged deg -> mrp-local + bsum2 + dinv ----
__global__ __launch_bounds__(256) void scans_kernel(int N, int NE) {
    __shared__ int sc[256];
    int t = threadIdx.x;
    int NC8 = (NE + 255) >> 8, NCM = (N + 255) >> 8;
    for (int vb = blockIdx.x; vb < NC8; vb += gridDim.x) {
        int idx = (vb << 8) + t;
        int d = (idx < NE) ? g_deg8[idx] : 0;
        sc[t] = d;
        __syncthreads();
        for (int off = 1; off < 256; off <<= 1) {
            int v = (t >= off) ? sc[t - off] : 0;
            __syncthreads();
            sc[t] += v;
            __syncthreads();
        }
        if (idx < NE) g_rowptr8[idx] = sc[t] - d;
        if (t == 255) g_bsum[vb] = sc[255];
        __syncthreads();
    }
    for (int vb = blockIdx.x; vb < NCM; vb += gridDim.x) {
        int idx = (vb << 8) + t;
        int d = 0;
        if (idx < N) {
#pragma unroll
            for (int g = 0; g < NGRP; g++) d += g_deg8[g * N + idx];
            g_dinv[idx] = rsqrtf((float)d + 1.0f);  // +1 = self loop
        }
        sc[t] = d;
        __syncthreads();
        for (int off = 1; off < 256; off <<= 1) {
            int v = (t >= off) ? sc[t - off] : 0;
            __syncthreads();
            sc[t] += v;
            __syncthreads();
        }
        if (idx < N) g_mrp[idx] = sc[t] - d;
        if (t == 255) g_bsum2[vb] = sc[255];
        __syncthreads();
    }
}

// ---- K4: block-sum scans for both arrays (single block) ----
__global__ __launch_bounds__(256) void bscans_kernel(int NB, int NB2, int NE, int N, int E) {
    __shared__ int sc[256];
    int t = threadIdx.x;
    {   // group-major bsum: 8 values/thread serial + one 256-scan
        int loc[8];
        int s = 0;
#pragma unroll
        for (int j = 0; j < 8; j++) {
            int i = t * 8 + j;
            int v = (i < NB) ? g_bsum[i] : 0;
            loc[j] = s;
            s += v;
        }
        sc[t] = s;
        __syncthreads();
        for (int off = 1; off < 256; off <<= 1) {
            int v = (t >= off) ? sc[t - off] : 0;
            __syncthreads();
            sc[t] += v;
            __syncthreads();
        }
        int excl = sc[t] - s;
#pragma unroll
        for (int j = 0; j < 8; j++) {
            int i = t * 8 + j;
            if (i < NB) g_boff[i] = excl + loc[j];
        }
        __syncthreads();
    }
    {   // merged bsum2 (<=256)
        int v = (t < NB2) ? g_bsum2[t] : 0;
        sc[t] = v;
        __syncthreads();
        for (int off = 1; off < 256; off <<= 1) {
            int u = (t >= off) ? sc[t - off] : 0;
            __syncthreads();
            sc[t] += u;
            __syncthreads();
        }
        if (t < NB2) g_boff2[t] = sc[t] - v;
    }
    if (t == 0) { g_rowptr8[NE] = E; g_mrp[N] = E; }
}

// ---- K5: add block offsets, finalize rowptr8+cursor8 and mrp ----
__global__ __launch_bounds__(256) void addoffs_kernel(int N, int NE) {
    int idx = blockIdx.x * 256 + threadIdx.x;
    if (idx < NE) {
        int base = g_rowptr8[idx] + g_boff[blockIdx.x];
        g_rowptr8[idx] = base;
        g_cursor8[idx] = base;
    }
    if ((int)blockIdx.x < (N + 255) / 256 && idx < (blockIdx.x + 1) * 256) {
        int i2 = idx;
        if (i2 < N) g_mrp[i2] += g_boff2[blockIdx.x];
    }
}

// ---- K6: scatter edges into group-partitioned CSR (src/dst direct from ei) ----
__global__ __launch_bounds__(256) void scatter_kernel(const void* __restrict__ ei, int N, int E) {
    int e = blockIdx.x * 256 + threadIdx.x;
    if (e < E) {
        int s, d;
        if (g_is64) { const long long* p = (const long long*)ei; s = (int)p[e]; d = (int)p[E + e]; }
        else        { const int* p = (const int*)ei; s = p[e]; d = p[E + e]; }
        int g = blockIdx.x & (NGRP - 1);
        int pos = atomicAdd(&g_cursor8[g * N + d], 1);
        g_csr[pos] = s;
    }
}

// ---- K7: merge group CSR -> node-major mcsr (wave/node) + zprep blocked ----
__global__ __launch_bounds__(256) void mergezp_kernel(const void* __restrict__ z, int N) {
    int gid = blockIdx.x * 256 + threadIdx.x;
    int wid = gid >> 6;
    int lane = threadIdx.x & 63;
    if (wid < N) {
        int mybeg = 0, mycnt = 0;
        if (lane < NGRP) {
            mybeg = g_rowptr8[lane * N + wid];
            mycnt = g_rowptr8[lane * N + wid + 1] - mybeg;
        }
        int incl = mycnt;
#pragma unroll
        for (int off = 1; off < NGRP; off <<= 1) {
            int v = __shfl_up(incl, off, 64);
            if (lane >= off) incl += v;
        }
        int myoff = incl - mycnt;
        int go[NGRP], gb[NGRP];
#pragma unroll
        for (int k = 0; k < NGRP; k++) {
            go[k] = __shfl(myoff, k, 64);
            gb[k] = __shfl(mybeg, k, 64);
        }
        int total = __shfl(incl, NGRP - 1, 64);
        int base = g_mrp[wid];
        for (int i = lane; i < total; i += 64) {
            int g = 0;
#pragma unroll
            for (int k = 1; k < NGRP; k++) g += (i >= go[k]);
            g_mcsr[base + i] = g_csr[gb[g] + i - go[g]];
        }
    }
    if (gid < N * IN_DIM) {
        int node = gid >> 6, c = gid & 63;
        int s = c >> 4, off = c & 15;
        g_agg1[(size_t)s * (N * 16) + node * 16 + off] = loadx(z, gid, g_in_f32) * g_dinv[node];
    }
}

// ---- K8/K10: block-staged sliced aggregation (16 nodes x 1 slice per block) ----
// slice pinned via blockIdx&3 -> per-XCD 3.2MB table stays L2-resident.
template <int LAYER2>
__global__ __launch_bounds__(256) void aggslc_kernel(void* __restrict__ outp, int N) {
    __shared__ int rp[NPB + 1];
    __shared__ int eidx[ECAP];
    int s = blockIdx.x & (NSLC - 1);
    int n0 = (blockIdx.x >> 2) * NPB;
    int t = threadIdx.x;
    if (t <= NPB) {
        int idx = n0 + t;
        rp[t] = g_mrp[idx <= N ? idx : N];
    }
    __syncthreads();
    int base = rp[0];
    int range = rp[NPB] - base;
    bool staged = (range <= ECAP);
    if (staged) {
        for (int i = t; i < range; i += 256) eidx[i] = g_mcsr[base + i];
    }
    __syncthreads();
    const float* tab = (LAYER2 ? g_hs1 : g_agg1) + (size_t)s * ((size_t)N * 16);
    int lane = t & 63;
    int w4 = (t >> 6) * 4;
    int col = lane & 15, eslot = lane >> 4;
    float res[4];
#pragma unroll
    for (int k = 0; k < 4; k++) {
        int jb = rp[w4 + k] - base + eslot;
        int je = rp[w4 + k + 1] - base;
        float a0 = 0.f, a1 = 0.f, a2 = 0.f, a3 = 0.f;
        int j = jb;
        if (staged) {
            for (; j + 12 < je; j += 16) {
                int i0 = eidx[j], i1 = eidx[j + 4], i2 = eidx[j + 8], i3 = eidx[j + 12];
                a0 += tab[i0 * 16 + col];
                a1 += tab[i1 * 16 + col];
                a2 += tab[i2 * 16 + col];
                a3 += tab[i3 * 16 + col];
            }
            for (; j < je; j += 4) a0 += tab[eidx[j] * 16 + col];
        } else {
            for (; j < je; j += 4) a0 += tab[g_mcsr[base + j] * 16 + col];
        }
        float a = (a0 + a1) + (a2 + a3);
        a += __shfl_xor(a, 16, 64);
        a += __shfl_xor(a, 32, 64);
        res[k] = a;
    }
    if (lane < 16) {
#pragma unroll
        for (int k = 0; k < 4; k++) {
            int nk = n0 + w4 + k;
            if (nk < N) {
                float v = (res[k] + tab[(size_t)nk * 16 + col]) * g_dinv[nk];
                if (LAYER2) {
                    v += g_b2f[s * 16 + col];
                    int oc = nk * 64 + s * 16 + col;
                    if (g_in_f32) ((float*)outp)[oc] = v;
                    else ((__hip_bfloat16*)outp)[oc] = __float2bfloat16(v);
                } else {
                    g_hs1[(size_t)s * ((size_t)N * 16) + nk * 16 + col] = v;
                }
            }
        }
    }
}

// ---- K9: FUSED MLP per 32-row block: hs2 = (relu(aggz@W1+b1))@W2 * dinv ----
// h never leaves LDS; input aggz (blocked g_hs1) overwritten in-place with hs2 (same rows).
__global__ __launch_bounds__(256) void gemm_fused_kernel(int N) {
    __shared__ float Zs[IN_DIM * 33];    // aggz^T  [64k][32r+pad]  8448 B
    __shared__ float Zh[HID_DIM * 33];   // h^T     [128k][32r+pad] 16896 B
    int t = threadIdx.x;
    int row0 = blockIdx.x * 32;
    // stage aggz (blocked [4][N][16]) transposed into Zs
#pragma unroll
    for (int s = 0; s < 2; s++) {
        int i = t + s * 256;              // 512 float4s = 32 rows x 16
        int r = i >> 4, k4 = i & 15;
        int row = row0 + r;
        int g = k4 >> 2, off = (k4 & 3) * 4;
        float4 v = make_float4(0.f, 0.f, 0.f, 0.f);
        if (row < N) v = *(const float4*)&g_hs1[(size_t)g * (N * 16) + row * 16 + off];
        Zs[(g * 16 + off + 0) * 33 + r] = v.x;
        Zs[(g * 16 + off + 1) * 33 + r] = v.y;
        Zs[(g * 16 + off + 2) * 33 + r] = v.z;
        Zs[(g * 16 + off + 3) * 33 + r] = v.w;
    }
    __syncthreads();
    // gemm1: 32 colgroups x 8 rowgroups, 4x4 micro-tile; h -> Zh transposed
    {
        int cg = t & 31, rg = t >> 5;
        int c0 = cg * 4, r0 = rg * 4;
        float acc[4][4] = {};
#pragma unroll 8
        for (int k = 0; k < IN_DIM; k++) {
            float b[4];
            *(float4*)b = *(const float4*)&g_W1f[k * HID_DIM + c0];
            float a[4];
            a[0] = Zs[k * 33 + r0];
            a[1] = Zs[k * 33 + r0 + 1];
            a[2] = Zs[k * 33 + r0 + 2];
            a[3] = Zs[k * 33 + r0 + 3];
#pragma unroll
            for (int i = 0; i < 4; i++)
#pragma unroll
                for (int j = 0; j < 4; j++) acc[i][j] = fmaf(a[i], b[j], acc[i][j]);
        }
        float4 bias = *(const float4*)&g_b1f[c0];
#pragma unroll
        for (int i = 0; i < 4; i++) {
            float bb[4] = {bias.x, bias.y, bias.z, bias.w};
#pragma unroll
            for (int j = 0; j < 4; j++)
                Zh[(c0 + j) * 33 + (r0 + i)] = fmaxf(acc[i][j] + bb[j], 0.f);
        }
    }
    __syncthreads();
    // gemm2: 16 colgroups x 16 rowgroups, 2x4 micro-tile; K=128 from Zh
    {
        int cg = t & 15, rg = t >> 4;
        int c0 = cg * 4, r0 = rg * 2;
        float acc[2][4] = {};
#pragma unroll 8
        for (int k2 = 0; k2 < HID_DIM; k2++) {
            float b[4];
            *(float4*)b = *(const float4*)&g_W2f[k2 * OUT_DIM + c0];
            float a0 = Zh[k2 * 33 + r0];
            float a1 = Zh[k2 * 33 + r0 + 1];
#pragma unroll
            for (int j = 0; j < 4; j++) {
                acc[0][j] = fmaf(a0, b[j], acc[0][j]);
                acc[1][j] = fmaf(a1, b[j], acc[1][j]);
            }
        }
        int g = cg >> 2, off = (cg & 3) * 4;  // blocked output [4][N][16]
#pragma unroll
        for (int i = 0; i < 2; i++) {
            int row = row0 + r0 + i;
            if (row < N) {
                float dn = g_dinv[row];
                float4 v;
                v.x = acc[i][0] * dn;
                v.y = acc[i][1] * dn;
                v.z = acc[i][2] * dn;
                v.w = acc[i][3] * dn;
                *(float4*)&g_hs1[(size_t)g * (N * 16) + row * 16 + off] = v;
            }
        }
    }
}

extern "C" void kernel_launch(void* const* d_in, const int* in_sizes, int n_in,
                              void* d_out, int out_size, void* d_ws, size_t ws_size,
                              hipStream_t stream) {
    const void* z  = d_in[0];
    const void* ei = d_in[1];
    const void* W1 = d_in[2];
    const void* b1 = d_in[3];
    const void* W2 = d_in[4];
    const void* b2 = d_in[5];

    const int N = in_sizes[0] / IN_DIM;  // 50000
    const int E = in_sizes[1] / 2;       // 800000
    const int NE = NGRP * N;             // 400000
    const int NC8 = (NE + 255) / 256;    // 1563
    const int NCM = (N + 255) / 256;     // 196
    const int aggblocks = NSLC * ((N + NPB - 1) / NPB);  // 12500

    zerodet_kernel<<<NC8, 256, 0, stream>>>((const unsigned short*)z, (const unsigned int*)ei, NE, E);
    degprep_kernel<<<(E + 255) / 256, 256, 0, stream>>>(ei, W1, b1, W2, b2, N, E);
    scans_kernel<<<NC8, 256, 0, stream>>>(N, NE);
    bscans_kernel<<<1, 256, 0, stream>>>(NC8, NCM, NE, N, E);
    addoffs_kernel<<<NC8, 256, 0, stream>>>(N, NE);
    scatter_kernel<<<(E + 255) / 256, 256, 0, stream>>>(ei, N, E);
    mergezp_kernel<<<(N * 64 + 255) / 256, 256, 0, stream>>>(z, N);

    aggslc_kernel<0><<<aggblocks, 256, 0, stream>>>(d_out, N);
    gemm_fused_kernel<<<(N + 31) / 32, 256, 0, stream>>>(N);
    aggslc_kernel<1><<<aggblocks, 256, 0, stream>>>(d_out, N);
}